// Round 1
// baseline (168.958 us; speedup 1.0000x reference)
//
#include <hip/hip_runtime.h>
#include <math.h>

// Problem constants (fixed by setup_inputs): B=16, C=1, H=W=512, M=500, DIM=7
namespace {
constexpr int Bc = 16;
constexpr int Mc = 500;
constexpr int Hc = 512;
constexpr int Wc = 512;
constexpr int HWc = Hc * Wc;
constexpr int Dc = 7;
constexpr int NPAIR = Bc * Mc;              // 8000
constexpr int BLOCK = 256;
constexpr int NBLK = (NPAIR + BLOCK - 1) / BLOCK;  // 32
}

// BEV intersection area of two rotated rectangles, replicating the reference
// algorithm (candidate points -> angle sort around centroid -> shoelace).
// box layout: x, y, z, dx, dy, dz, heading
__device__ float bev_inter(const float* __restrict__ a, const float* __restrict__ b) {
    const float cA = cosf(a[6]), sA = sinf(a[6]);
    const float cB = cosf(b[6]), sB = sinf(b[6]);

    // corner template rows: (0.5,0.5), (-0.5,0.5), (-0.5,-0.5), (0.5,-0.5)
    const float t0[4] = {0.5f, -0.5f, -0.5f, 0.5f};
    const float t1[4] = {0.5f, 0.5f, -0.5f, -0.5f};

    float cax[4], cay[4], cbx[4], cby[4];
#pragma unroll
    for (int i = 0; i < 4; ++i) {
        float lx = t0[i] * a[3], ly = t1[i] * a[4];
        cax[i] = lx * cA - ly * sA + a[0];
        cay[i] = lx * sA + ly * cA + a[1];
        lx = t0[i] * b[3]; ly = t1[i] * b[4];
        cbx[i] = lx * cB - ly * sB + b[0];
        cby[i] = lx * sB + ly * cB + b[1];
    }

    float px[24], py[24];
    int n = 0;

    // corners of A inside B (rotate into B frame, half-extent test + 1e-5 tol)
    const float hbx = b[3] * 0.5f + 1e-5f, hby = b[4] * 0.5f + 1e-5f;
#pragma unroll
    for (int i = 0; i < 4; ++i) {
        float dx = cax[i] - b[0], dy = cay[i] - b[1];
        float qx = dx * cB + dy * sB;
        float qy = -dx * sB + dy * cB;
        if (fabsf(qx) <= hbx && fabsf(qy) <= hby) { px[n] = cax[i]; py[n] = cay[i]; ++n; }
    }
    // corners of B inside A
    const float hax = a[3] * 0.5f + 1e-5f, hay = a[4] * 0.5f + 1e-5f;
#pragma unroll
    for (int i = 0; i < 4; ++i) {
        float dx = cbx[i] - a[0], dy = cby[i] - a[1];
        float qx = dx * cA + dy * sA;
        float qy = -dx * sA + dy * cA;
        if (fabsf(qx) <= hax && fabsf(qy) <= hay) { px[n] = cbx[i]; py[n] = cby[i]; ++n; }
    }
    // 16 edge-edge intersections
#pragma unroll
    for (int i = 0; i < 4; ++i) {
        const float p1x = cax[i], p1y = cay[i];
        const float d1x = cax[(i + 1) & 3] - p1x, d1y = cay[(i + 1) & 3] - p1y;
#pragma unroll
        for (int j = 0; j < 4; ++j) {
            const float q1x = cbx[j], q1y = cby[j];
            const float d2x = cbx[(j + 1) & 3] - q1x, d2y = cby[(j + 1) & 3] - q1y;
            const float den = d1x * d2y - d1y * d2x;
            if (fabsf(den) > 1e-8f) {
                const float rx = q1x - p1x, ry = q1y - p1y;
                const float t = (rx * d2y - ry * d2x) / den;
                const float u = (rx * d1y - ry * d1x) / den;
                if (t >= -1e-6f && t <= 1.f + 1e-6f && u >= -1e-6f && u <= 1.f + 1e-6f) {
                    px[n] = p1x + t * d1x;
                    py[n] = p1y + t * d1y;
                    ++n;
                }
            }
        }
    }

    if (n < 3) return 0.f;

    float cx = 0.f, cy = 0.f;
    for (int k = 0; k < n; ++k) { cx += px[k]; cy += py[k]; }
    const float inv_n = 1.f / (float)n;
    cx *= inv_n; cy *= inv_n;

    float ang[24];
    for (int k = 0; k < n; ++k) ang[k] = atan2f(py[k] - cy, px[k] - cx);

    // insertion sort by angle (stable; duplicates are harmless for shoelace)
    for (int k = 1; k < n; ++k) {
        const float ka = ang[k], kx = px[k], ky = py[k];
        int j = k - 1;
        while (j >= 0 && ang[j] > ka) {
            ang[j + 1] = ang[j]; px[j + 1] = px[j]; py[j + 1] = py[j];
            --j;
        }
        ang[j + 1] = ka; px[j + 1] = kx; py[j + 1] = ky;
    }

    float area = 0.f;
    for (int k = 0; k < n; ++k) {
        const int k2 = (k + 1 == n) ? 0 : k + 1;
        area += px[k] * py[k2] - py[k] * px[k2];
    }
    return 0.5f * fabsf(area);
}

__device__ float iou3d(const float* __restrict__ a, const float* __restrict__ b) {
    const float inter_bev = bev_inter(a, b);
    const float top = fminf(a[2] + a[5] * 0.5f, b[2] + b[5] * 0.5f);
    const float bot = fmaxf(a[2] - a[5] * 0.5f, b[2] - b[5] * 0.5f);
    const float inter = inter_bev * fmaxf(top - bot, 0.f);
    const float va = a[3] * a[4] * a[5];
    const float vb = b[3] * b[4] * b[5];
    return inter / fmaxf(va + vb - inter, 1e-6f);
}

__global__ void __launch_bounds__(BLOCK)
iou_loss_pairs(const float* __restrict__ iou_pred,
               const int* __restrict__ mask,
               const int* __restrict__ ind,
               const float* __restrict__ box_pred,
               const float* __restrict__ box_gt,
               float* __restrict__ ws) {
    const int idx = blockIdx.x * BLOCK + threadIdx.x;
    float term = 0.f, mv = 0.f;
    if (idx < NPAIR) {
        const int b = idx / Mc;
        const int i = ind[idx];
        const float pred = iou_pred[(size_t)b * HWc + i];

        float pb[7], gb[7];
        const float* bp = box_pred + (size_t)b * Dc * HWc + i;
#pragma unroll
        for (int d = 0; d < 7; ++d) pb[d] = bp[(size_t)d * HWc];
#pragma unroll
        for (int d = 0; d < 7; ++d) gb[d] = box_gt[(size_t)idx * 7 + d];

        const float iou = iou3d(pb, gb);
        const float target = 2.f * iou - 1.f;
        const float mm = (float)mask[idx];
        term = fabsf(pred - target) * mm;
        mv = mm;
    }

    // wave (64-lane) reduction, then cross-wave via LDS
#pragma unroll
    for (int off = 32; off > 0; off >>= 1) {
        term += __shfl_down(term, off);
        mv += __shfl_down(mv, off);
    }
    __shared__ float st[BLOCK / 64], sm[BLOCK / 64];
    const int wave = threadIdx.x >> 6, lane = threadIdx.x & 63;
    if (lane == 0) { st[wave] = term; sm[wave] = mv; }
    __syncthreads();
    if (threadIdx.x == 0) {
        float t = 0.f, m = 0.f;
#pragma unroll
        for (int w = 0; w < BLOCK / 64; ++w) { t += st[w]; m += sm[w]; }
        ws[blockIdx.x * 2] = t;
        ws[blockIdx.x * 2 + 1] = m;
    }
}

__global__ void iou_loss_finalize(const float* __restrict__ ws, float* __restrict__ out) {
    const int t = threadIdx.x;  // 64 threads
    float s = (t < NBLK) ? ws[t * 2] : 0.f;
    float m = (t < NBLK) ? ws[t * 2 + 1] : 0.f;
#pragma unroll
    for (int off = 32; off > 0; off >>= 1) {
        s += __shfl_down(s, off);
        m += __shfl_down(m, off);
    }
    if (t == 0) out[0] = s / (m + 1e-4f);
}

extern "C" void kernel_launch(void* const* d_in, const int* in_sizes, int n_in,
                              void* d_out, int out_size, void* d_ws, size_t ws_size,
                              hipStream_t stream) {
    const float* iou_pred = (const float*)d_in[0];
    const int* mask = (const int*)d_in[1];
    const int* ind = (const int*)d_in[2];
    const float* box_pred = (const float*)d_in[3];
    const float* box_gt = (const float*)d_in[4];
    float* ws = (float*)d_ws;
    float* out = (float*)d_out;

    iou_loss_pairs<<<NBLK, BLOCK, 0, stream>>>(iou_pred, mask, ind, box_pred, box_gt, ws);
    iou_loss_finalize<<<1, 64, 0, stream>>>(ws, out);
}

// Round 2
// 160.993 us; speedup vs baseline: 1.0495x; 1.0495x over previous
//
#include <hip/hip_runtime.h>
#include <math.h>

// Problem constants (fixed by setup_inputs): B=16, C=1, H=W=512, M=500, DIM=7
namespace {
constexpr int Bc = 16;
constexpr int Mc = 500;
constexpr int Hc = 512;
constexpr int Wc = 512;
constexpr int HWc = Hc * Wc;
constexpr int Dc = 7;
constexpr int NPAIR = Bc * Mc;              // 8000
constexpr int BLOCK = 64;                   // 1 wave/block -> 125 blocks spread over CUs
constexpr int NBLK = (NPAIR + BLOCK - 1) / BLOCK;  // 125
}

// Append a point to a register-resident 8-slot polygon. Fully unrolled select
// chain: all array indices are compile-time constants, so the arrays stay in
// VGPRs (no scratch).
__device__ __forceinline__ void push_pt(float (&qx)[8], float (&qy)[8], int& m,
                                        float nx, float ny) {
#pragma unroll
    for (int s = 0; s < 8; ++s) {
        if (s == m) { qx[s] = nx; qy[s] = ny; }
    }
    ++m;
}

// One Sutherland-Hodgman pass: clip polygon (Px,Py,n) against half-plane
// sx*x + sy*y <= lim. (sx,sy,lim) are wave-uniform compile-time-foldable.
__device__ __forceinline__ void clip_pass(float (&Px)[8], float (&Py)[8], int& n,
                                          float sx, float sy, float lim) {
    float Qx[8], Qy[8];
    int m = 0;
    const int nn = n;
#pragma unroll
    for (int k = 0; k < 8; ++k) {
        if (k < nn) {
            const float cx = Px[k], cy = Py[k];
            float nx, ny;
            if (k == 7) { nx = Px[0]; ny = Py[0]; }
            else if (k + 1 == nn) { nx = Px[0]; ny = Py[0]; }
            else { nx = Px[k + 1]; ny = Py[k + 1]; }
            const float dc = lim - (sx * cx + sy * cy);  // >=0 : inside
            const float dn = lim - (sx * nx + sy * ny);
            const bool cin = dc >= 0.f;
            const bool nin = dn >= 0.f;
            if (cin) push_pt(Qx, Qy, m, cx, cy);
            if (cin != nin) {
                const float t = dc / (dc - dn);  // denom != 0 when signs differ
                push_pt(Qx, Qy, m, cx + t * (nx - cx), cy + t * (ny - cy));
            }
        }
    }
    n = m;
#pragma unroll
    for (int k = 0; k < 8; ++k) { Px[k] = Qx[k]; Py[k] = Qy[k]; }
}

// BEV intersection area of two rotated rectangles via polygon clipping in
// box-b's local frame (b becomes axis-aligned). Rotation-invariant, so area
// equals the reference's world-frame computation up to fp rounding.
__device__ float bev_inter(const float* __restrict__ a, const float* __restrict__ b) {
    float sA, cA, sB, cB;
    __sincosf(a[6], &sA, &cA);
    __sincosf(b[6], &sB, &cB);
    // relative rotation R(-hB)*R(hA)
    const float cR = cA * cB + sA * sB;
    const float sR = sA * cB - cA * sB;
    // a's center in b's frame
    const float dxw = a[0] - b[0], dyw = a[1] - b[1];
    const float ox = dxw * cB + dyw * sB;
    const float oy = -dxw * sB + dyw * cB;

    // a's corners in b's frame; corner template (±0.5, ±0.5) CCW
    const float t0[4] = {0.5f, -0.5f, -0.5f, 0.5f};
    const float t1[4] = {0.5f, 0.5f, -0.5f, -0.5f};
    float Px[8], Py[8];
#pragma unroll
    for (int i = 0; i < 4; ++i) {
        const float lx = t0[i] * a[3], ly = t1[i] * a[4];
        Px[i] = lx * cR - ly * sR + ox;
        Py[i] = lx * sR + ly * cR + oy;
    }
#pragma unroll
    for (int i = 4; i < 8; ++i) { Px[i] = 0.f; Py[i] = 0.f; }
    int n = 4;

    const float hx = b[3] * 0.5f, hy = b[4] * 0.5f;
    clip_pass(Px, Py, n, 1.f, 0.f, hx);    //  x <= hx
    clip_pass(Px, Py, n, -1.f, 0.f, hx);   // -x <= hx
    clip_pass(Px, Py, n, 0.f, 1.f, hy);    //  y <= hy
    clip_pass(Px, Py, n, 0.f, -1.f, hy);   // -y <= hy

    // shoelace over the (convex, CCW) clipped polygon; n<3 gives 0 naturally
    float area2 = 0.f;
#pragma unroll
    for (int k = 0; k < 8; ++k) {
        if (k < n) {
            float nx, ny;
            if (k == 7) { nx = Px[0]; ny = Py[0]; }
            else if (k + 1 == n) { nx = Px[0]; ny = Py[0]; }
            else { nx = Px[k + 1]; ny = Py[k + 1]; }
            area2 += Px[k] * ny - Py[k] * nx;
        }
    }
    return 0.5f * fabsf(area2);
}

__device__ float iou3d(const float* __restrict__ a, const float* __restrict__ b) {
    const float inter_bev = bev_inter(a, b);
    const float top = fminf(a[2] + a[5] * 0.5f, b[2] + b[5] * 0.5f);
    const float bot = fmaxf(a[2] - a[5] * 0.5f, b[2] - b[5] * 0.5f);
    const float inter = inter_bev * fmaxf(top - bot, 0.f);
    const float va = a[3] * a[4] * a[5];
    const float vb = b[3] * b[4] * b[5];
    return inter / fmaxf(va + vb - inter, 1e-6f);
}

__global__ void __launch_bounds__(BLOCK)
iou_loss_pairs(const float* __restrict__ iou_pred,
               const int* __restrict__ mask,
               const int* __restrict__ ind,
               const float* __restrict__ box_pred,
               const float* __restrict__ box_gt,
               float* __restrict__ ws) {
    const int idx = blockIdx.x * BLOCK + threadIdx.x;
    float term = 0.f, mv = 0.f;
    if (idx < NPAIR) {
        const int b = idx / Mc;
        const int i = ind[idx];
        const float pred = iou_pred[(size_t)b * HWc + i];

        float pb[7], gb[7];
        const float* bp = box_pred + (size_t)b * Dc * HWc + i;
#pragma unroll
        for (int d = 0; d < 7; ++d) pb[d] = bp[(size_t)d * HWc];
#pragma unroll
        for (int d = 0; d < 7; ++d) gb[d] = box_gt[(size_t)idx * 7 + d];

        const float iou = iou3d(pb, gb);
        const float target = 2.f * iou - 1.f;
        const float mm = (float)mask[idx];
        term = fabsf(pred - target) * mm;
        mv = mm;
    }

    // single-wave block: pure shuffle reduction, no LDS round-trip
#pragma unroll
    for (int off = 32; off > 0; off >>= 1) {
        term += __shfl_down(term, off);
        mv += __shfl_down(mv, off);
    }
    if (threadIdx.x == 0) {
        ws[blockIdx.x] = term;
        ws[128 + blockIdx.x] = mv;
    }
}

__global__ void iou_loss_finalize(const float* __restrict__ ws, float* __restrict__ out) {
    const int t = threadIdx.x;  // 64 threads
    float s = 0.f, m = 0.f;
    for (int i = t; i < NBLK; i += 64) {
        s += ws[i];
        m += ws[128 + i];
    }
#pragma unroll
    for (int off = 32; off > 0; off >>= 1) {
        s += __shfl_down(s, off);
        m += __shfl_down(m, off);
    }
    if (t == 0) out[0] = s / (m + 1e-4f);
}

extern "C" void kernel_launch(void* const* d_in, const int* in_sizes, int n_in,
                              void* d_out, int out_size, void* d_ws, size_t ws_size,
                              hipStream_t stream) {
    const float* iou_pred = (const float*)d_in[0];
    const int* mask = (const int*)d_in[1];
    const int* ind = (const int*)d_in[2];
    const float* box_pred = (const float*)d_in[3];
    const float* box_gt = (const float*)d_in[4];
    float* ws = (float*)d_ws;
    float* out = (float*)d_out;

    iou_loss_pairs<<<NBLK, BLOCK, 0, stream>>>(iou_pred, mask, ind, box_pred, box_gt, ws);
    iou_loss_finalize<<<1, 64, 0, stream>>>(ws, out);
}